// Round 5
// baseline (444.217 us; speedup 1.0000x reference)
//
#include <hip/hip_runtime.h>

typedef unsigned short u16;
typedef __attribute__((ext_vector_type(8))) short short8;
typedef __attribute__((ext_vector_type(4))) float f32x4;

constexpr int B_ = 2;
constexpr int H_ = 8;
constexpr int KVH_ = 4;
constexpr int S_ = 2048;
constexpr int D_ = 256;
constexpr int HID_ = 2304;
constexpr int QKVN_ = 4096;   // 2048 q + 1024 k + 1024 v
constexpr int AON_ = 2048;    // H_*D_

__device__ __forceinline__ float b2f(u16 u) {
  union { float f; unsigned int i; } x; x.i = ((unsigned int)u) << 16; return x.f;
}
__device__ __forceinline__ u16 f2b(float f) {
  unsigned int x = __float_as_uint(f);
  unsigned int r = (x + 0x7fffu + ((x >> 16) & 1u)) >> 16;
  return (u16)r;
}

// ---------------- cast fp32 -> bf16 (vectorized) ----------------
__global__ void cast_kernel(const float* __restrict__ in, u16* __restrict__ out) {
  size_t i = ((size_t)blockIdx.x * 256 + threadIdx.x) * 4;
  float4 v = *(const float4*)(in + i);
  unsigned int lo = (unsigned int)f2b(v.x) | ((unsigned int)f2b(v.y) << 16);
  unsigned int hi = (unsigned int)f2b(v.z) | ((unsigned int)f2b(v.w) << 16);
  uint2 o; o.x = lo; o.y = hi;
  *(uint2*)(out + i) = o;
}

// ---------------- all 4 weight transposes in ONE launch ----------------
__global__ void transpose_cast_all(const float* __restrict__ s0, const float* __restrict__ s1,
                                   const float* __restrict__ s2, const float* __restrict__ s3,
                                   u16* __restrict__ d0, u16* __restrict__ d1,
                                   u16* __restrict__ d2, u16* __restrict__ d3) {
  __shared__ float tile[64][65];
  int which = blockIdx.z;
  const float* src; u16* dst; int R, C;
  if (which == 0)      { src = s0; dst = d0; R = 2304; C = 2048; }
  else if (which == 1) { src = s1; dst = d1; R = 2304; C = 1024; }
  else if (which == 2) { src = s2; dst = d2; R = 2304; C = 1024; }
  else                 { src = s3; dst = d3; R = 2048; C = 2304; }
  int r0 = blockIdx.y * 64, c0 = blockIdx.x * 64;
  if (r0 >= R || c0 >= C) return;
  int t = threadIdx.x;
#pragma unroll
  for (int i = 0; i < 16; ++i) {
    int e = i * 256 + t;
    int r = e >> 6, c = e & 63;
    tile[r][c] = src[(size_t)(r0 + r) * C + (c0 + c)];
  }
  __syncthreads();
#pragma unroll
  for (int i = 0; i < 16; ++i) {
    int e = i * 256 + t;
    int orow = e >> 6, ocol = e & 63;
    dst[(size_t)(c0 + orow) * R + (r0 + ocol)] = f2b(tile[ocol][orow]);
  }
}

// ---------------- 256x256-tile 8-wave 4-phase/K-tile bf16 GEMM (m201-style) ----
template <int OUTF32>
__global__ __launch_bounds__(512, 2) void gemm_bt8(
    const u16* __restrict__ A, const u16* __restrict__ B, void* __restrict__ Cp,
    int M, int N, int K) {
  __shared__ u16 lds[2][2][2][8192];  // [buf][0=A,1=B][half(128 rows)][16 KiB]
  const int tid = threadIdx.x;
  const int lane = tid & 63;
  const int wave = tid >> 6;
  const int wm = wave >> 2, wn = wave & 3;       // 2 (M) x 4 (N) waves
  const int quad = lane >> 4, l16 = lane & 15;
  const int m0 = blockIdx.y * 256, n0 = blockIdx.x * 256;
  const int nt = K >> 6;  // K-tiles of 64

  const int sub = tid >> 6;
  const int rr = (tid >> 2) & 15;
  const int cc = ((tid & 3) * 8) ^ ((rr & 8) ? 16 : 0);
  const int r_rel = (sub >> 1) * 16 + rr;   // 0..63 row within region
  const int ccol = (sub & 1) * 32 + cc;     // 0..63 k-col (pre-inverse-swizzled)
  const u16* Asrc = A + (size_t)(m0 + r_rel) * K + ccol;
  const u16* Bsrc = B + (size_t)(n0 + r_rel) * K + ccol;
  const int ldsc = tid * 8;  // u16 index of this thread's 16 B chunk in a region

  const int fr_off = l16 * 64 + (((quad * 8) ^ ((l16 & 8) ? 16 : 0)) << 1);

#define GL8(src, dst)                                                                  \
  __builtin_amdgcn_global_load_lds((const __attribute__((address_space(1))) void*)(src), \
                                   (__attribute__((address_space(3))) void*)(dst), 16, 0, 0)
#define STAGE_A(bf, kt, qp) {                                                          \
    const u16* _s = Asrc + (size_t)(kt) * 64;                                          \
    GL8(_s + (size_t)((qp) * 64) * K,       &lds[bf][0][0][(qp) * 4096 + ldsc]);       \
    GL8(_s + (size_t)(128 + (qp) * 64) * K, &lds[bf][0][1][(qp) * 4096 + ldsc]); }
#define STAGE_B(bf, kt, hf) {                                                          \
    const u16* _s = Bsrc + (size_t)(kt) * 64;                                          \
    GL8(_s + (size_t)((hf) * 128) * K,      &lds[bf][1][hf][ldsc]);                    \
    GL8(_s + (size_t)((hf) * 128 + 64) * K, &lds[bf][1][hf][4096 + ldsc]); }
#define LDA(bf, mi, kk) \
  (*(const short8*)((const char*)&lds[bf][0][wm][0] + (mi) * 2048 + (kk) * 1024 + fr_off))
#define LDB(bf, ni, kk) \
  (*(const short8*)((const char*)&lds[bf][1][wn >> 1][0] + ((wn & 1) * 4 + (ni)) * 2048 + (kk) * 1024 + fr_off))

  f32x4 acc[8][4] = {};
  short8 bfr[4][2], af[2][2];

  STAGE_B(0, 0, 0); STAGE_B(0, 0, 1); STAGE_A(0, 0, 0); STAGE_A(0, 0, 1);
  STAGE_B(1, 1, 0); STAGE_B(1, 1, 1); STAGE_A(1, 1, 0);
  asm volatile("s_waitcnt vmcnt(6)" ::: "memory");
  __builtin_amdgcn_s_barrier();

#define PHASE(q, STG, VMW)                                                             \
    _Pragma("unroll") for (int i = 0; i < 2; ++i)                                      \
      _Pragma("unroll") for (int kk = 0; kk < 2; ++kk) af[i][kk] = LDA(c, 2 * (q) + i, kk); \
    STG; VMW;                                                                          \
    __builtin_amdgcn_s_barrier();                                                      \
    asm volatile("s_waitcnt lgkmcnt(0)" ::: "memory");                                 \
    __builtin_amdgcn_sched_barrier(0);                                                 \
    __builtin_amdgcn_s_setprio(1);                                                     \
    _Pragma("unroll") for (int i = 0; i < 2; ++i)                                      \
      _Pragma("unroll") for (int ni = 0; ni < 4; ++ni)                                 \
        _Pragma("unroll") for (int kk = 0; kk < 2; ++kk)                               \
          acc[2 * (q) + i][ni] = __builtin_amdgcn_mfma_f32_16x16x32_bf16(              \
              af[i][kk], bfr[ni][kk], acc[2 * (q) + i][ni], 0, 0, 0);                  \
    __builtin_amdgcn_s_setprio(0);                                                     \
    __builtin_amdgcn_s_barrier();

  for (int T = 0; T < nt; ++T) {
    const int c = T & 1;
#pragma unroll
    for (int ni = 0; ni < 4; ++ni)
#pragma unroll
      for (int kk = 0; kk < 2; ++kk) bfr[ni][kk] = LDB(c, ni, kk);
    PHASE(0, if (T + 1 < nt) STAGE_A(c ^ 1, T + 1, 1), )
    PHASE(1, if (T + 2 < nt) STAGE_B(c, T + 2, 0), )
    PHASE(2, if (T + 2 < nt) STAGE_B(c, T + 2, 1), )
    PHASE(3, if (T + 2 < nt) STAGE_A(c, T + 2, 0),
          if (T + 2 >= nt) { asm volatile("s_waitcnt vmcnt(0)" ::: "memory"); }
          else             { asm volatile("s_waitcnt vmcnt(6)" ::: "memory"); })
  }
#undef PHASE
#undef LDA
#undef LDB
#undef STAGE_A
#undef STAGE_B
#undef GL8

#pragma unroll
  for (int mi = 0; mi < 8; ++mi) {
#pragma unroll
    for (int ni = 0; ni < 4; ++ni) {
#pragma unroll
      for (int r = 0; r < 4; ++r) {
        int row = m0 + wm * 128 + mi * 16 + quad * 4 + r;
        int col = n0 + wn * 64 + ni * 16 + l16;
        if (OUTF32)
          ((float*)Cp)[(size_t)row * N + col] = acc[mi][ni][r];
        else
          ((u16*)Cp)[(size_t)row * N + col] = f2b(acc[mi][ni][r]);
      }
    }
  }
}

// ---------------- RoPE + rearrange ----------------
__global__ void rope_kernel(const u16* __restrict__ qkv, const float* __restrict__ cs,
                            const float* __restrict__ sn, u16* __restrict__ Qr,
                            u16* __restrict__ Kr) {
  int row = blockIdx.x;          // b*S + s
  int b = row >> 11, s = row & 2047;
  int d = threadIdx.x;           // 0..255
  const u16* qrow = qkv + (size_t)row * QKVN_;
  float c = cs[(size_t)row * D_ + d];
  float si = sn[(size_t)row * D_ + d];
  int dp = (d < 128) ? d + 128 : d - 128;
  float sgn = (d < 128) ? -1.f : 1.f;
#pragma unroll
  for (int h = 0; h < H_; ++h) {
    float v = b2f(qrow[h * D_ + d]);
    float p = sgn * b2f(qrow[h * D_ + dp]);
    Qr[((size_t)(b * H_ + h) * S_ + s) * D_ + d] = f2b(v * c + p * si);
  }
#pragma unroll
  for (int g = 0; g < KVH_; ++g) {
    float v = b2f(qrow[2048 + g * D_ + d]);
    float p = sgn * b2f(qrow[2048 + g * D_ + dp]);
    Kr[((size_t)(b * KVH_ + g) * S_ + s) * D_ + d] = f2b(v * c + p * si);
  }
}

// ---------------- V transpose: qkv v-part -> Vt (B,KVH,D,S) ----------------
__global__ void transpose_v(const u16* __restrict__ qkv, u16* __restrict__ Vt) {
  __shared__ u16 tile[64][72];
  int d0 = blockIdx.x * 64, s0 = blockIdx.y * 64, g = blockIdx.z; // g = b*KVH+kvh
  int b = g >> 2, kvh = g & 3;
  int t = threadIdx.x;
#pragma unroll
  for (int i = 0; i < 16; ++i) {
    int e = i * 256 + t;
    int r = e >> 6, c = e & 63;
    tile[r][c] = qkv[(size_t)(b * S_ + s0 + r) * QKVN_ + 3072 + kvh * D_ + d0 + c];
  }
  __syncthreads();
#pragma unroll
  for (int i = 0; i < 16; ++i) {
    int e = i * 256 + t;
    int orow = e >> 6, ocol = e & 63;
    Vt[((size_t)g * D_ + d0 + orow) * S_ + s0 + ocol] = tile[ocol][orow];
  }
}

// ---------------- flash attention v11: uniform 8-wave blocks, D-split PV -----
// v10 lesson: dispatch-order pairing is unreliable; only identical-work blocks
// give stable occupancy (v8's property). With 2 O-partials, uniform 4-wave
// grids are stuck at 256 blocks (1 wave/SIMD, v9-toxic). Escape: split PV's
// OUTPUT D (dsp): block computes full QK^T but only 128 of 256 d-columns.
// dsp blocks write DISJOINT columns of the same Op[sp] -> still 2 partials.
// Block = 8 waves x 32q = 256-row q-tile; part-loop fold: partA (b=0,qt=u)
// sp-half (4u+4 iters) + partB (b=1,qt=7-u) sp-half (32-4u) = 36 iters, ALL
// 256 blocks identical. Grid 256 = 1 block/CU = 2 waves/SIMD, no assumptions.
// Per wave-iter: 24 ds_read_b128 (16 K + 8 half-V) -> 48 MFMA.
__global__ __launch_bounds__(512, 2) void attn_kernel(
    const u16* __restrict__ Qr, const u16* __restrict__ Kr, const u16* __restrict__ Vt,
    float* __restrict__ Op0, float* __restrict__ Op1,
    float* __restrict__ Lp0, float* __restrict__ Lp1) {
  __shared__ u16 Ks[2][32 * 256];  // 2x16 KB, chunk-swizzled (^ sw(row))
  __shared__ u16 Vs[2][128 * 32];  // 2x8 KB (128 d-rows x 32 keys), chunk-swizzled
  int bx = blockIdx.x;
  int h = bx >> 5;
  int dsp = (bx >> 4) & 1;
  int sp = (bx >> 3) & 1;
  int u = bx & 7;
  int kvh = h >> 1;  // N_REP = 2
  int tid = threadIdx.x, wave = tid >> 6, lane = tid & 63;
  int quad = lane >> 4, l16 = lane & 15;
  float* Op = sp ? Op1 : Op0;
  float* Lp = sp ? Lp1 : Lp0;
  // staging address pieces (512 threads):
  //   V (8KB): p=tid, d=p>>2 (0..127), chunk c=(p&3)^((d>>1)&3)=(p&3)^((p>>3)&3)
  const int vd = tid >> 2;
  const int vc = (tid & 3) ^ ((tid >> 3) & 3);
  // K-fragment read geometry (swapped-QK, row-permuted read):
  const int kg = l16 >> 2, ka = l16 & 3;
  const int srow0 = 8 * kg + ka;           // n=0; n=1 adds 4
  const int ksw = ka | ((kg & 1) << 2);    // column swizzle of that row

  for (int part = 0; part < 2; ++part) {
    int b = part;
    int qt = part ? (7 - u) : u;
    int q0 = qt * 256;
    int nh = 4 * qt + 4;                 // sp-half length in kv-tiles of 32
    int beg = sp ? nh : 0;
    int end = sp ? (2 * nh) : nh;
    const u16* Qbase = Qr + ((size_t)(b * H_ + h) * S_ + q0 + wave * 32 + l16) * D_;
    short8 qf[2][8];
#pragma unroll
    for (int f = 0; f < 2; ++f)
#pragma unroll
      for (int kk = 0; kk < 8; ++kk)
        qf[f][kk] = *(const short8*)(Qbase + (size_t)f * 16 * D_ + kk * 32 + quad * 8);
    const u16* Kbase = Kr + (size_t)(b * KVH_ + kvh) * S_ * D_;
    const u16* Vbase = Vt + ((size_t)(b * KVH_ + kvh) * D_ + dsp * 128) * S_;
    float lp[2] = {0.f, 0.f};
    f32x4 o_acc[2][8] = {};
    const int qq0 = q0 + wave * 32 + l16;

#define STAGE(KT, BUF)                                                                   \
    {                                                                                    \
      int k0s = (KT) * 32;                                                               \
      _Pragma("unroll") for (int i = 0; i < 2; ++i) {                                    \
        int p = i * 512 + tid;                                                           \
        int ks = p >> 5;                                                                 \
        int kc = (p & 31) ^ ((ks & 3) | (((ks >> 3) & 1) << 2));                         \
        __builtin_amdgcn_global_load_lds(                                                \
            (const __attribute__((address_space(1))) void*)(Kbase +                      \
                (size_t)(k0s + ks) * D_ + kc * 8),                                       \
            (__attribute__((address_space(3))) void*)(&Ks[BUF][0] + p * 8), 16, 0, 0);   \
      }                                                                                  \
      __builtin_amdgcn_global_load_lds(                                                  \
          (const __attribute__((address_space(1))) void*)(Vbase +                        \
              (size_t)vd * S_ + k0s + vc * 8),                                           \
          (__attribute__((address_space(3))) void*)(&Vs[BUF][0] + tid * 8), 16, 0, 0);   \
    }

    STAGE(beg, 0);
    __syncthreads();  // first tile staged (safe vs prev part: loop-end barrier passed)
    for (int kt = beg; kt < end; ++kt) {
      int k0 = kt * 32;
      int cur = (kt - beg) & 1;
      if (kt + 1 < end) STAGE(kt + 1, cur ^ 1);
      // S^T = K Q^T for both q-frags; each kfr used twice
      f32x4 sacc[2][2] = {};  // [f][n]
      __builtin_amdgcn_s_setprio(1);
#pragma unroll
      for (int n = 0; n < 2; ++n) {
        const u16* kb = &Ks[cur][0] + (srow0 + 4 * n) * 256;
#pragma unroll
        for (int kk = 0; kk < 8; ++kk) {
          int phys = (kk * 4 + quad) ^ ksw;
          short8 kfr = *(const short8*)(kb + phys * 8);
          sacc[0][n] = __builtin_amdgcn_mfma_f32_16x16x32_bf16(kfr, qf[0][kk], sacc[0][n], 0, 0, 0);
          sacc[1][n] = __builtin_amdgcn_mfma_f32_16x16x32_bf16(kfr, qf[1][kk], sacc[1][n], 0, 0, 0);
        }
      }
      __builtin_amdgcn_s_setprio(0);
      // fused softcap+softmax: ee = exp(-100/(E+1)), E=exp(s*0.0025)
      bool full = (k0 + 31 <= q0 + wave * 32);  // wave-uniform (min q row of wave)
      short8 pa[2];
#pragma unroll
      for (int f = 0; f < 2; ++f) {
        union { short8 s8; unsigned int d[4]; } pu;
#pragma unroll
        for (int n = 0; n < 2; ++n) {
#pragma unroll
          for (int rr2 = 0; rr2 < 4; ++rr2) {
            float E = __expf(sacc[f][n][rr2] * 0.0025f);
            float ee = __expf(-100.0f * __frcp_rn(E + 1.0f));
            if (!full) {
              int key = k0 + 8 * quad + 4 * n + rr2;  // lane holds keys 8*quad + 4n + r
              ee = (key <= qq0 + f * 16) ? ee : 0.0f;
            }
            lp[f] += ee;
            sacc[f][n][rr2] = ee;
          }
          pu.d[2 * n]     = (unsigned int)f2b(sacc[f][n][0]) | ((unsigned int)f2b(sacc[f][n][1]) << 16);
          pu.d[2 * n + 1] = (unsigned int)f2b(sacc[f][n][2]) | ((unsigned int)f2b(sacc[f][n][3]) << 16);
        }
        pa[f] = pu.s8;
      }
      // O += P V on this block's 128 d-columns; each vb used twice
      __builtin_amdgcn_s_setprio(1);
#pragma unroll
      for (int dt = 0; dt < 8; ++dt) {
        int d = dt * 16 + l16;
        int phys = quad ^ ((d >> 1) & 3);
        short8 vb = *(const short8*)(&Vs[cur][0] + d * 32 + phys * 8);
        o_acc[0][dt] = __builtin_amdgcn_mfma_f32_16x16x32_bf16(pa[0], vb, o_acc[0][dt], 0, 0, 0);
        o_acc[1][dt] = __builtin_amdgcn_mfma_f32_16x16x32_bf16(pa[1], vb, o_acc[1][dt], 0, 0, 0);
      }
      __builtin_amdgcn_s_setprio(0);
      __syncthreads();  // buffer handoff (prefetch long since landed)
    }
#undef STAGE
    // denominator partials (only dsp==0 writes; dsp==1 computes identical values)
#pragma unroll
    for (int f = 0; f < 2; ++f) {
      lp[f] += __shfl_xor(lp[f], 16, 64);
      lp[f] += __shfl_xor(lp[f], 32, 64);
    }
    if (dsp == 0 && lane < 16) {
      size_t lb = ((size_t)(b * H_ + h)) * S_ + q0 + wave * 32 + lane;
      Lp[lb] = lp[0];
      Lp[lb + 16] = lp[1];
    }
    // unnormalized fp32 partial O (this block's half of d)
#pragma unroll
    for (int f = 0; f < 2; ++f)
#pragma unroll
      for (int dt = 0; dt < 8; ++dt)
#pragma unroll
        for (int rr2 = 0; rr2 < 4; ++rr2) {
          int row = b * S_ + q0 + wave * 32 + f * 16 + quad * 4 + rr2;
          int col = h * D_ + dsp * 128 + dt * 16 + l16;
          Op[(size_t)row * AON_ + col] = o_acc[f][dt][rr2];
        }
  }
}

// ---------------- combine splits: Ao = (O0+O1) / (l0+l1), bf16 ----------------
__global__ void combine_kernel(const float* __restrict__ Op0, const float* __restrict__ Op1,
                               const float* __restrict__ Lp0, const float* __restrict__ Lp1,
                               u16* __restrict__ Ao) {
  size_t idx = (size_t)blockIdx.x * 256 + threadIdx.x;
  size_t row = idx >> 9;
  int c4 = ((int)idx & 511) * 4;
  const float4 a = *(const float4*)(Op0 + row * AON_ + c4);
  const float4 b4 = *(const float4*)(Op1 + row * AON_ + c4);
  int b = (int)(row >> 11), s = (int)row & 2047;
  int h = c4 >> 8;
  size_t li = ((size_t)(b * H_ + h)) * S_ + s;
  float inv = 1.0f / (Lp0[li] + Lp1[li]);
  unsigned int lo = (unsigned int)f2b((a.x + b4.x) * inv) | ((unsigned int)f2b((a.y + b4.y) * inv) << 16);
  unsigned int hi = (unsigned int)f2b((a.z + b4.z) * inv) | ((unsigned int)f2b((a.w + b4.w) * inv) << 16);
  uint2 o; o.x = lo; o.y = hi;
  *(uint2*)(Ao + row * AON_ + c4) = o;
}

extern "C" void kernel_launch(void* const* d_in, const int* in_sizes, int n_in,
                              void* d_out, int out_size, void* d_ws, size_t ws_size,
                              hipStream_t stream) {
  const float* hidden = (const float*)d_in[0];
  const float* cosp = (const float*)d_in[1];
  const float* sinp = (const float*)d_in[2];
  const float* Wq = (const float*)d_in[4];
  const float* Wk = (const float*)d_in[5];
  const float* Wv = (const float*)d_in[6];
  const float* Wo = (const float*)d_in[7];

  u16* hs  = (u16*)d_ws;                              // 4096 x 2304 (dead after gemm1)
  u16* WT  = hs  + (size_t)4096 * HID_;               // 4096 x 2304 (dead after gemm1)
  u16* WoT = WT  + (size_t)4096 * HID_;               // 2304 x 2048 (live till gemm2)
  u16* qkv = WoT + (size_t)HID_ * AON_;               // 4096 x 4096 (dead after rope/transpose_v)
  u16* Qr  = qkv + (size_t)4096 * QKVN_;              // B,H,S,D
  u16* Kr  = Qr  + (size_t)B_ * H_ * S_ * D_;         // B,KVH,S,D
  u16* Vt  = Kr  + (size_t)B_ * KVH_ * S_ * D_;       // B,KVH,D,S
  u16* Ao  = Vt  + (size_t)B_ * KVH_ * S_ * D_;       // 4096 x 2048
  float* Lp0 = (float*)(Ao + (size_t)4096 * AON_);    // 2*8*2048 fp32
  float* Lp1 = Lp0 + (size_t)B_ * H_ * S_;            // 2*8*2048 fp32
  float* Op0 = (float*)hs;    // hs+WT region: 37.7 MB available >= 33.5
  float* Op1 = (float*)qkv;   // qkv region: 33.5 MB, exact fit

  cast_kernel<<<9216, 256, 0, stream>>>(hidden, hs);
  transpose_cast_all<<<dim3(36, 36, 4), 256, 0, stream>>>(
      Wq, Wk, Wv, Wo, WT, WT + (size_t)2048 * HID_, WT + (size_t)3072 * HID_, WoT);
  gemm_bt8<0><<<dim3(16, 16), 512, 0, stream>>>(hs, WT, qkv, 4096, QKVN_, HID_);
  rope_kernel<<<4096, 256, 0, stream>>>(qkv, cosp, sinp, Qr, Kr);
  transpose_v<<<dim3(4, 32, 8), 256, 0, stream>>>(qkv, Vt);
  attn_kernel<<<dim3(256), 512, 0, stream>>>(Qr, Kr, Vt, Op0, Op1, Lp0, Lp1);
  combine_kernel<<<16384, 256, 0, stream>>>(Op0, Op1, Lp0, Lp1, Ao);
  gemm_bt8<1><<<dim3(9, 16), 512, 0, stream>>>(Ao, WoT, d_out, 4096, HID_, 2048);
}

// Round 6
// 398.665 us; speedup vs baseline: 1.1143x; 1.1143x over previous
//
#include <hip/hip_runtime.h>

typedef unsigned short u16;
typedef __attribute__((ext_vector_type(8))) short short8;
typedef __attribute__((ext_vector_type(4))) float f32x4;

constexpr int B_ = 2;
constexpr int H_ = 8;
constexpr int KVH_ = 4;
constexpr int S_ = 2048;
constexpr int D_ = 256;
constexpr int HID_ = 2304;
constexpr int QKVN_ = 4096;   // 2048 q + 1024 k + 1024 v
constexpr int AON_ = 2048;    // H_*D_

__device__ __forceinline__ float b2f(u16 u) {
  union { float f; unsigned int i; } x; x.i = ((unsigned int)u) << 16; return x.f;
}
__device__ __forceinline__ u16 f2b(float f) {
  unsigned int x = __float_as_uint(f);
  unsigned int r = (x + 0x7fffu + ((x >> 16) & 1u)) >> 16;
  return (u16)r;
}

// ---------------- cast fp32 -> bf16 (vectorized) ----------------
__global__ void cast_kernel(const float* __restrict__ in, u16* __restrict__ out) {
  size_t i = ((size_t)blockIdx.x * 256 + threadIdx.x) * 4;
  float4 v = *(const float4*)(in + i);
  unsigned int lo = (unsigned int)f2b(v.x) | ((unsigned int)f2b(v.y) << 16);
  unsigned int hi = (unsigned int)f2b(v.z) | ((unsigned int)f2b(v.w) << 16);
  uint2 o; o.x = lo; o.y = hi;
  *(uint2*)(out + i) = o;
}

// ---------------- all 4 weight transposes in ONE launch ----------------
__global__ void transpose_cast_all(const float* __restrict__ s0, const float* __restrict__ s1,
                                   const float* __restrict__ s2, const float* __restrict__ s3,
                                   u16* __restrict__ d0, u16* __restrict__ d1,
                                   u16* __restrict__ d2, u16* __restrict__ d3) {
  __shared__ float tile[64][65];
  int which = blockIdx.z;
  const float* src; u16* dst; int R, C;
  if (which == 0)      { src = s0; dst = d0; R = 2304; C = 2048; }
  else if (which == 1) { src = s1; dst = d1; R = 2304; C = 1024; }
  else if (which == 2) { src = s2; dst = d2; R = 2304; C = 1024; }
  else                 { src = s3; dst = d3; R = 2048; C = 2304; }
  int r0 = blockIdx.y * 64, c0 = blockIdx.x * 64;
  if (r0 >= R || c0 >= C) return;
  int t = threadIdx.x;
#pragma unroll
  for (int i = 0; i < 16; ++i) {
    int e = i * 256 + t;
    int r = e >> 6, c = e & 63;
    tile[r][c] = src[(size_t)(r0 + r) * C + (c0 + c)];
  }
  __syncthreads();
#pragma unroll
  for (int i = 0; i < 16; ++i) {
    int e = i * 256 + t;
    int orow = e >> 6, ocol = e & 63;
    dst[(size_t)(c0 + orow) * R + (r0 + ocol)] = f2b(tile[ocol][orow]);
  }
}

// ---------------- 256x256-tile 8-wave 4-phase/K-tile bf16 GEMM (m201-style) ----
template <int OUTF32>
__global__ __launch_bounds__(512, 2) void gemm_bt8(
    const u16* __restrict__ A, const u16* __restrict__ B, void* __restrict__ Cp,
    int M, int N, int K) {
  __shared__ u16 lds[2][2][2][8192];  // [buf][0=A,1=B][half(128 rows)][16 KiB]
  const int tid = threadIdx.x;
  const int lane = tid & 63;
  const int wave = tid >> 6;
  const int wm = wave >> 2, wn = wave & 3;       // 2 (M) x 4 (N) waves
  const int quad = lane >> 4, l16 = lane & 15;
  const int m0 = blockIdx.y * 256, n0 = blockIdx.x * 256;
  const int nt = K >> 6;  // K-tiles of 64

  const int sub = tid >> 6;
  const int rr = (tid >> 2) & 15;
  const int cc = ((tid & 3) * 8) ^ ((rr & 8) ? 16 : 0);
  const int r_rel = (sub >> 1) * 16 + rr;   // 0..63 row within region
  const int ccol = (sub & 1) * 32 + cc;     // 0..63 k-col (pre-inverse-swizzled)
  const u16* Asrc = A + (size_t)(m0 + r_rel) * K + ccol;
  const u16* Bsrc = B + (size_t)(n0 + r_rel) * K + ccol;
  const int ldsc = tid * 8;  // u16 index of this thread's 16 B chunk in a region

  const int fr_off = l16 * 64 + (((quad * 8) ^ ((l16 & 8) ? 16 : 0)) << 1);

#define GL8(src, dst)                                                                  \
  __builtin_amdgcn_global_load_lds((const __attribute__((address_space(1))) void*)(src), \
                                   (__attribute__((address_space(3))) void*)(dst), 16, 0, 0)
#define STAGE_A(bf, kt, qp) {                                                          \
    const u16* _s = Asrc + (size_t)(kt) * 64;                                          \
    GL8(_s + (size_t)((qp) * 64) * K,       &lds[bf][0][0][(qp) * 4096 + ldsc]);       \
    GL8(_s + (size_t)(128 + (qp) * 64) * K, &lds[bf][0][1][(qp) * 4096 + ldsc]); }
#define STAGE_B(bf, kt, hf) {                                                          \
    const u16* _s = Bsrc + (size_t)(kt) * 64;                                          \
    GL8(_s + (size_t)((hf) * 128) * K,      &lds[bf][1][hf][ldsc]);                    \
    GL8(_s + (size_t)((hf) * 128 + 64) * K, &lds[bf][1][hf][4096 + ldsc]); }
#define LDA(bf, mi, kk) \
  (*(const short8*)((const char*)&lds[bf][0][wm][0] + (mi) * 2048 + (kk) * 1024 + fr_off))
#define LDB(bf, ni, kk) \
  (*(const short8*)((const char*)&lds[bf][1][wn >> 1][0] + ((wn & 1) * 4 + (ni)) * 2048 + (kk) * 1024 + fr_off))

  f32x4 acc[8][4] = {};
  short8 bfr[4][2], af[2][2];

  STAGE_B(0, 0, 0); STAGE_B(0, 0, 1); STAGE_A(0, 0, 0); STAGE_A(0, 0, 1);
  STAGE_B(1, 1, 0); STAGE_B(1, 1, 1); STAGE_A(1, 1, 0);
  asm volatile("s_waitcnt vmcnt(6)" ::: "memory");
  __builtin_amdgcn_s_barrier();

#define PHASE(q, STG, VMW)                                                             \
    _Pragma("unroll") for (int i = 0; i < 2; ++i)                                      \
      _Pragma("unroll") for (int kk = 0; kk < 2; ++kk) af[i][kk] = LDA(c, 2 * (q) + i, kk); \
    STG; VMW;                                                                          \
    __builtin_amdgcn_s_barrier();                                                      \
    asm volatile("s_waitcnt lgkmcnt(0)" ::: "memory");                                 \
    __builtin_amdgcn_sched_barrier(0);                                                 \
    __builtin_amdgcn_s_setprio(1);                                                     \
    _Pragma("unroll") for (int i = 0; i < 2; ++i)                                      \
      _Pragma("unroll") for (int ni = 0; ni < 4; ++ni)                                 \
        _Pragma("unroll") for (int kk = 0; kk < 2; ++kk)                               \
          acc[2 * (q) + i][ni] = __builtin_amdgcn_mfma_f32_16x16x32_bf16(              \
              af[i][kk], bfr[ni][kk], acc[2 * (q) + i][ni], 0, 0, 0);                  \
    __builtin_amdgcn_s_setprio(0);                                                     \
    __builtin_amdgcn_s_barrier();

  for (int T = 0; T < nt; ++T) {
    const int c = T & 1;
#pragma unroll
    for (int ni = 0; ni < 4; ++ni)
#pragma unroll
      for (int kk = 0; kk < 2; ++kk) bfr[ni][kk] = LDB(c, ni, kk);
    PHASE(0, if (T + 1 < nt) STAGE_A(c ^ 1, T + 1, 1), )
    PHASE(1, if (T + 2 < nt) STAGE_B(c, T + 2, 0), )
    PHASE(2, if (T + 2 < nt) STAGE_B(c, T + 2, 1), )
    PHASE(3, if (T + 2 < nt) STAGE_A(c, T + 2, 0),
          if (T + 2 >= nt) { asm volatile("s_waitcnt vmcnt(0)" ::: "memory"); }
          else             { asm volatile("s_waitcnt vmcnt(6)" ::: "memory"); })
  }
#undef PHASE
#undef LDA
#undef LDB
#undef STAGE_A
#undef STAGE_B
#undef GL8

#pragma unroll
  for (int mi = 0; mi < 8; ++mi) {
#pragma unroll
    for (int ni = 0; ni < 4; ++ni) {
#pragma unroll
      for (int r = 0; r < 4; ++r) {
        int row = m0 + wm * 128 + mi * 16 + quad * 4 + r;
        int col = n0 + wn * 64 + ni * 16 + l16;
        if (OUTF32)
          ((float*)Cp)[(size_t)row * N + col] = acc[mi][ni][r];
        else
          ((u16*)Cp)[(size_t)row * N + col] = f2b(acc[mi][ni][r]);
      }
    }
  }
}

// ---------------- RoPE + rearrange ----------------
__global__ void rope_kernel(const u16* __restrict__ qkv, const float* __restrict__ cs,
                            const float* __restrict__ sn, u16* __restrict__ Qr,
                            u16* __restrict__ Kr) {
  int row = blockIdx.x;          // b*S + s
  int b = row >> 11, s = row & 2047;
  int d = threadIdx.x;           // 0..255
  const u16* qrow = qkv + (size_t)row * QKVN_;
  float c = cs[(size_t)row * D_ + d];
  float si = sn[(size_t)row * D_ + d];
  int dp = (d < 128) ? d + 128 : d - 128;
  float sgn = (d < 128) ? -1.f : 1.f;
#pragma unroll
  for (int h = 0; h < H_; ++h) {
    float v = b2f(qrow[h * D_ + d]);
    float p = sgn * b2f(qrow[h * D_ + dp]);
    Qr[((size_t)(b * H_ + h) * S_ + s) * D_ + d] = f2b(v * c + p * si);
  }
#pragma unroll
  for (int g = 0; g < KVH_; ++g) {
    float v = b2f(qrow[2048 + g * D_ + d]);
    float p = sgn * b2f(qrow[2048 + g * D_ + dp]);
    Kr[((size_t)(b * KVH_ + g) * S_ + s) * D_ + d] = f2b(v * c + p * si);
  }
}

// ---------------- V transpose: qkv v-part -> Vt (B,KVH,D,S) ----------------
__global__ void transpose_v(const u16* __restrict__ qkv, u16* __restrict__ Vt) {
  __shared__ u16 tile[64][72];
  int d0 = blockIdx.x * 64, s0 = blockIdx.y * 64, g = blockIdx.z; // g = b*KVH+kvh
  int b = g >> 2, kvh = g & 3;
  int t = threadIdx.x;
#pragma unroll
  for (int i = 0; i < 16; ++i) {
    int e = i * 256 + t;
    int r = e >> 6, c = e & 63;
    tile[r][c] = qkv[(size_t)(b * S_ + s0 + r) * QKVN_ + 3072 + kvh * D_ + d0 + c];
  }
  __syncthreads();
#pragma unroll
  for (int i = 0; i < 16; ++i) {
    int e = i * 256 + t;
    int orow = e >> 6, ocol = e & 63;
    Vt[((size_t)g * D_ + d0 + orow) * S_ + s0 + ocol] = tile[ocol][orow];
  }
}

// ---------------- flash attention v8b: v8 (proven 83.9us) + XCD h-pinning ----
// v8 is at its structural LDS floor (4.19M MFMA x 1024B/MFMA / 85B/cyc/CU /
// 256CU ~= 82us). v9-v11 restructures all regressed (occupancy / imbalance /
// redundant-QK). v8b keeps v8 byte-identical except the grid: 1D 512 blocks
// with h = bx&7, so the 64 blocks sharing one h's 4MB K/V working set land on
// one XCD (dispatch round-robin: XCD = bx%8) -> KV L2-resident per XCD.
// v8 FETCH was 100MB vs 33.6MB ideal; expect ~half the overfetch to vanish.
__global__ __launch_bounds__(256, 2) void attn_kernel(
    const u16* __restrict__ Qr, const u16* __restrict__ Kr, const u16* __restrict__ Vt,
    float* __restrict__ Op0, float* __restrict__ Op1,
    float* __restrict__ Lp0, float* __restrict__ Lp1) {
  __shared__ u16 Ks[2][32 * 256]; // 2x16 KB, chunk-swizzled (^ sw(row))
  __shared__ u16 Vs[2][32 * 256]; // 2x16 KB, chunk-swizzled (^ (d>>1)&3)
  int bx = blockIdx.x;
  int h = bx & 7;                 // XCD pin: round-robin dispatch -> XCD = bx%8
  int u = bx >> 4;
  int sp = (bx >> 3) & 1;
  int kvh = h >> 1;  // N_REP = 2
  int tid = threadIdx.x, wave = tid >> 6, lane = tid & 63;
  int quad = lane >> 4, l16 = lane & 15;
  float* Op = sp ? Op1 : Op0;
  float* Lp = sp ? Lp1 : Lp0;
  int ksrc_s[4], ksrc_c[4], vsrc_d[4], vsrc_s[4];
#pragma unroll
  for (int i = 0; i < 4; ++i) {
    int p = i * 256 + tid;
    int sK = p >> 5;
    ksrc_s[i] = sK;
    ksrc_c[i] = (p & 31) ^ ((sK & 3) | (((sK >> 3) & 1) << 2));
    vsrc_d[i] = p >> 2;
    vsrc_s[i] = (p & 3) ^ ((p >> 3) & 3);
  }
  // K-fragment read geometry (swapped-QK, permuted rows):
  const int kg = l16 >> 2, ka = l16 & 3;
  const int srow0 = 8 * kg + ka;           // n=0; n=1 adds 4
  const int ksw = ka | ((kg & 1) << 2);    // sw(srow), same for n=0,1

  for (int part = 0; part < 2; ++part) {
    int b = part;
    int qt = (part == 0) ? u : (31 - u);
    int q0 = qt * 64;
    int beg = sp ? (qt + 1) : 0;
    int end = sp ? (2 * qt + 2) : (qt + 1);
    const u16* Qbase = Qr + ((size_t)(b * H_ + h) * S_ + q0 + wave * 16 + l16) * D_;
    short8 qf[8];
#pragma unroll
    for (int kk = 0; kk < 8; ++kk)
      qf[kk] = *(const short8*)(Qbase + kk * 32 + quad * 8);
    const u16* Kbase = Kr + (size_t)(b * KVH_ + kvh) * S_ * D_;
    const u16* Vbase = Vt + (size_t)(b * KVH_ + kvh) * D_ * S_;
    float lp = 0.f;
    f32x4 o_acc[16] = {};
    const int qq = q0 + wave * 16 + l16;

#define STAGE(KT, BUF)                                                                   \
    {                                                                                    \
      int k0s = (KT) * 32;                                                               \
      _Pragma("unroll") for (int i = 0; i < 4; ++i) {                                    \
        int p = i * 256 + tid;                                                           \
        __builtin_amdgcn_global_load_lds(                                                \
            (const __attribute__((address_space(1))) void*)(Kbase +                      \
                (size_t)(k0s + ksrc_s[i]) * D_ + ksrc_c[i] * 8),                         \
            (__attribute__((address_space(3))) void*)(&Ks[BUF][0] + p * 8), 16, 0, 0);   \
      }                                                                                  \
      _Pragma("unroll") for (int i = 0; i < 4; ++i) {                                    \
        int p = i * 256 + tid;                                                           \
        __builtin_amdgcn_global_load_lds(                                                \
            (const __attribute__((address_space(1))) void*)(Vbase +                      \
                (size_t)vsrc_d[i] * S_ + k0s + vsrc_s[i] * 8),                           \
            (__attribute__((address_space(3))) void*)(&Vs[BUF][0] + p * 8), 16, 0, 0);   \
      }                                                                                  \
    }

    STAGE(beg, 0);
    __syncthreads();
    for (int kt = beg; kt < end; ++kt) {
      int k0 = kt * 32;
      int cur = (kt - beg) & 1;
      if (kt + 1 < end) STAGE(kt + 1, cur ^ 1);
      // S^T = K Q^T (A = permuted K-tile, B = Q)
      f32x4 sacc[2] = {};
      __builtin_amdgcn_s_setprio(1);
#pragma unroll
      for (int n = 0; n < 2; ++n) {
        const u16* kb = &Ks[cur][0] + (srow0 + 4 * n) * 256;
#pragma unroll
        for (int kk = 0; kk < 8; ++kk) {
          int phys = (kk * 4 + quad) ^ ksw;
          short8 kfr = *(const short8*)(kb + phys * 8);
          sacc[n] = __builtin_amdgcn_mfma_f32_16x16x32_bf16(kfr, qf[kk], sacc[n], 0, 0, 0);
        }
      }
      __builtin_amdgcn_s_setprio(0);
      // fused softcap+softmax: ee = exp(50*tanh(s/16/50)-50) = exp(-100/(E+1)), E=exp(s*0.0025)
      bool full = (k0 + 31 <= q0 + wave * 16);  // wave-uniform
#pragma unroll
      for (int n = 0; n < 2; ++n) {
#pragma unroll
        for (int r = 0; r < 4; ++r) {
          float E = __expf(sacc[n][r] * 0.0025f);
          float ee = __expf(-100.0f * __frcp_rn(E + 1.0f));
          if (!full) {
            int key = k0 + 8 * quad + 4 * n + r;   // lane holds keys 8*quad + 4n + r
            ee = (key <= qq) ? ee : 0.0f;
          }
          lp += ee;
          sacc[n][r] = ee;
        }
      }
      // pack P in-register: frag elem j = key 8*quad+j, j = 4n+r
      union { short8 s8; unsigned int d[4]; } pu;
      pu.d[0] = (unsigned int)f2b(sacc[0][0]) | ((unsigned int)f2b(sacc[0][1]) << 16);
      pu.d[1] = (unsigned int)f2b(sacc[0][2]) | ((unsigned int)f2b(sacc[0][3]) << 16);
      pu.d[2] = (unsigned int)f2b(sacc[1][0]) | ((unsigned int)f2b(sacc[1][1]) << 16);
      pu.d[3] = (unsigned int)f2b(sacc[1][2]) | ((unsigned int)f2b(sacc[1][3]) << 16);
      short8 pa = pu.s8;
      // O += P V  (pa is PV's A-fragment directly; no LDS round-trip)
      __builtin_amdgcn_s_setprio(1);
#pragma unroll
      for (int dt = 0; dt < 16; ++dt) {
        int d = dt * 16 + l16;
        int phys = quad ^ ((d >> 1) & 3);
        short8 vb = *(const short8*)(&Vs[cur][0] + d * 32 + phys * 8);
        o_acc[dt] = __builtin_amdgcn_mfma_f32_16x16x32_bf16(pa, vb, o_acc[dt], 0, 0, 0);
      }
      __builtin_amdgcn_s_setprio(0);
      __syncthreads();  // buffer handoff (prefetch long since landed)
    }
#undef STAGE
    // denominator partial: lane holds sum for q=l16 over its 8 keys/iter; reduce quads
    lp += __shfl_xor(lp, 16, 64);
    lp += __shfl_xor(lp, 32, 64);
    if (lane < 16)
      Lp[((size_t)(b * H_ + h)) * S_ + q0 + wave * 16 + lane] = lp;
    // unnormalized fp32 partial O (row q = quad*4+r, col d = dt*16+l16)
#pragma unroll
    for (int dt = 0; dt < 16; ++dt)
#pragma unroll
      for (int r = 0; r < 4; ++r) {
        int row = b * S_ + q0 + wave * 16 + quad * 4 + r;
        int col = h * D_ + dt * 16 + l16;
        Op[(size_t)row * AON_ + col] = o_acc[dt][r];
      }
  }
}

// ---------------- combine splits: Ao = (O0+O1) / (l0+l1), bf16 ----------------
__global__ void combine_kernel(const float* __restrict__ Op0, const float* __restrict__ Op1,
                               const float* __restrict__ Lp0, const float* __restrict__ Lp1,
                               u16* __restrict__ Ao) {
  size_t idx = (size_t)blockIdx.x * 256 + threadIdx.x;
  size_t row = idx >> 9;
  int c4 = ((int)idx & 511) * 4;
  const float4 a = *(const float4*)(Op0 + row * AON_ + c4);
  const float4 b4 = *(const float4*)(Op1 + row * AON_ + c4);
  int b = (int)(row >> 11), s = (int)row & 2047;
  int h = c4 >> 8;
  size_t li = ((size_t)(b * H_ + h)) * S_ + s;
  float inv = 1.0f / (Lp0[li] + Lp1[li]);
  unsigned int lo = (unsigned int)f2b((a.x + b4.x) * inv) | ((unsigned int)f2b((a.y + b4.y) * inv) << 16);
  unsigned int hi = (unsigned int)f2b((a.z + b4.z) * inv) | ((unsigned int)f2b((a.w + b4.w) * inv) << 16);
  uint2 o; o.x = lo; o.y = hi;
  *(uint2*)(Ao + row * AON_ + c4) = o;
}

extern "C" void kernel_launch(void* const* d_in, const int* in_sizes, int n_in,
                              void* d_out, int out_size, void* d_ws, size_t ws_size,
                              hipStream_t stream) {
  const float* hidden = (const float*)d_in[0];
  const float* cosp = (const float*)d_in[1];
  const float* sinp = (const float*)d_in[2];
  const float* Wq = (const float*)d_in[4];
  const float* Wk = (const float*)d_in[5];
  const float* Wv = (const float*)d_in[6];
  const float* Wo = (const float*)d_in[7];

  u16* hs  = (u16*)d_ws;                              // 4096 x 2304 (dead after gemm1)
  u16* WT  = hs  + (size_t)4096 * HID_;               // 4096 x 2304 (dead after gemm1)
  u16* WoT = WT  + (size_t)4096 * HID_;               // 2304 x 2048 (live till gemm2)
  u16* qkv = WoT + (size_t)HID_ * AON_;               // 4096 x 4096 (dead after rope/transpose_v)
  u16* Qr  = qkv + (size_t)4096 * QKVN_;              // B,H,S,D
  u16* Kr  = Qr  + (size_t)B_ * H_ * S_ * D_;         // B,KVH,S,D
  u16* Vt  = Kr  + (size_t)B_ * KVH_ * S_ * D_;       // B,KVH,D,S
  u16* Ao  = Vt  + (size_t)B_ * KVH_ * S_ * D_;       // 4096 x 2048
  float* Lp0 = (float*)(Ao + (size_t)4096 * AON_);    // 2*8*2048 fp32
  float* Lp1 = Lp0 + (size_t)B_ * H_ * S_;            // 2*8*2048 fp32
  float* Op0 = (float*)hs;    // hs+WT region: 37.7 MB available >= 33.5
  float* Op1 = (float*)qkv;   // qkv region: 33.5 MB, exact fit

  cast_kernel<<<9216, 256, 0, stream>>>(hidden, hs);
  transpose_cast_all<<<dim3(36, 36, 4), 256, 0, stream>>>(
      Wq, Wk, Wv, Wo, WT, WT + (size_t)2048 * HID_, WT + (size_t)3072 * HID_, WoT);
  gemm_bt8<0><<<dim3(16, 16), 512, 0, stream>>>(hs, WT, qkv, 4096, QKVN_, HID_);
  rope_kernel<<<4096, 256, 0, stream>>>(qkv, cosp, sinp, Qr, Kr);
  transpose_v<<<dim3(4, 32, 8), 256, 0, stream>>>(qkv, Vt);
  attn_kernel<<<dim3(512), 256, 0, stream>>>(Qr, Kr, Vt, Op0, Op1, Lp0, Lp1);
  combine_kernel<<<16384, 256, 0, stream>>>(Op0, Op1, Lp0, Lp1, Ao);
  gemm_bt8<1><<<dim3(9, 16), 512, 0, stream>>>(Ao, WoT, d_out, 4096, HID_, 2048);
}

// Round 7
// 396.366 us; speedup vs baseline: 1.1207x; 1.0058x over previous
//
#include <hip/hip_runtime.h>

typedef unsigned short u16;
typedef __attribute__((ext_vector_type(8))) short short8;
typedef __attribute__((ext_vector_type(4))) float f32x4;

constexpr int B_ = 2;
constexpr int H_ = 8;
constexpr int KVH_ = 4;
constexpr int S_ = 2048;
constexpr int D_ = 256;
constexpr int HID_ = 2304;
constexpr int QKVN_ = 4096;   // 2048 q + 1024 k + 1024 v
constexpr int AON_ = 2048;    // H_*D_

__device__ __forceinline__ float b2f(u16 u) {
  union { float f; unsigned int i; } x; x.i = ((unsigned int)u) << 16; return x.f;
}
__device__ __forceinline__ u16 f2b(float f) {
  unsigned int x = __float_as_uint(f);
  unsigned int r = (x + 0x7fffu + ((x >> 16) & 1u)) >> 16;
  return (u16)r;
}
// raw v_exp_f32: computes 2^x (no ln2 conversion mul)
__device__ __forceinline__ float exp2_raw(float x) {
  float r;
  asm("v_exp_f32 %0, %1" : "=v"(r) : "v"(x));
  return r;
}
// packed f32x2 -> bf16x2 (RTNE, identical result to f2b pair)
__device__ __forceinline__ unsigned int cvt_pk_bf16(float lo, float hi) {
  unsigned int r;
  asm("v_cvt_pk_bf16_f32 %0, %1, %2" : "=v"(r) : "v"(lo), "v"(hi));
  return r;
}

// ---------------- cast fp32 -> bf16 (vectorized) ----------------
__global__ void cast_kernel(const float* __restrict__ in, u16* __restrict__ out) {
  size_t i = ((size_t)blockIdx.x * 256 + threadIdx.x) * 4;
  float4 v = *(const float4*)(in + i);
  unsigned int lo = (unsigned int)f2b(v.x) | ((unsigned int)f2b(v.y) << 16);
  unsigned int hi = (unsigned int)f2b(v.z) | ((unsigned int)f2b(v.w) << 16);
  uint2 o; o.x = lo; o.y = hi;
  *(uint2*)(out + i) = o;
}

// ---------------- all 4 weight transposes in ONE launch ----------------
__global__ void transpose_cast_all(const float* __restrict__ s0, const float* __restrict__ s1,
                                   const float* __restrict__ s2, const float* __restrict__ s3,
                                   u16* __restrict__ d0, u16* __restrict__ d1,
                                   u16* __restrict__ d2, u16* __restrict__ d3) {
  __shared__ float tile[64][65];
  int which = blockIdx.z;
  const float* src; u16* dst; int R, C;
  if (which == 0)      { src = s0; dst = d0; R = 2304; C = 2048; }
  else if (which == 1) { src = s1; dst = d1; R = 2304; C = 1024; }
  else if (which == 2) { src = s2; dst = d2; R = 2304; C = 1024; }
  else                 { src = s3; dst = d3; R = 2048; C = 2304; }
  int r0 = blockIdx.y * 64, c0 = blockIdx.x * 64;
  if (r0 >= R || c0 >= C) return;
  int t = threadIdx.x;
#pragma unroll
  for (int i = 0; i < 16; ++i) {
    int e = i * 256 + t;
    int r = e >> 6, c = e & 63;
    tile[r][c] = src[(size_t)(r0 + r) * C + (c0 + c)];
  }
  __syncthreads();
#pragma unroll
  for (int i = 0; i < 16; ++i) {
    int e = i * 256 + t;
    int orow = e >> 6, ocol = e & 63;
    dst[(size_t)(c0 + orow) * R + (r0 + ocol)] = f2b(tile[ocol][orow]);
  }
}

// ---------------- 256x256-tile 8-wave 4-phase/K-tile bf16 GEMM (m201-style) ----
template <int OUTF32>
__global__ __launch_bounds__(512, 2) void gemm_bt8(
    const u16* __restrict__ A, const u16* __restrict__ B, void* __restrict__ Cp,
    int M, int N, int K) {
  __shared__ u16 lds[2][2][2][8192];  // [buf][0=A,1=B][half(128 rows)][16 KiB]
  const int tid = threadIdx.x;
  const int lane = tid & 63;
  const int wave = tid >> 6;
  const int wm = wave >> 2, wn = wave & 3;       // 2 (M) x 4 (N) waves
  const int quad = lane >> 4, l16 = lane & 15;
  const int m0 = blockIdx.y * 256, n0 = blockIdx.x * 256;
  const int nt = K >> 6;  // K-tiles of 64

  const int sub = tid >> 6;
  const int rr = (tid >> 2) & 15;
  const int cc = ((tid & 3) * 8) ^ ((rr & 8) ? 16 : 0);
  const int r_rel = (sub >> 1) * 16 + rr;   // 0..63 row within region
  const int ccol = (sub & 1) * 32 + cc;     // 0..63 k-col (pre-inverse-swizzled)
  const u16* Asrc = A + (size_t)(m0 + r_rel) * K + ccol;
  const u16* Bsrc = B + (size_t)(n0 + r_rel) * K + ccol;
  const int ldsc = tid * 8;  // u16 index of this thread's 16 B chunk in a region

  const int fr_off = l16 * 64 + (((quad * 8) ^ ((l16 & 8) ? 16 : 0)) << 1);

#define GL8(src, dst)                                                                  \
  __builtin_amdgcn_global_load_lds((const __attribute__((address_space(1))) void*)(src), \
                                   (__attribute__((address_space(3))) void*)(dst), 16, 0, 0)
#define STAGE_A(bf, kt, qp) {                                                          \
    const u16* _s = Asrc + (size_t)(kt) * 64;                                          \
    GL8(_s + (size_t)((qp) * 64) * K,       &lds[bf][0][0][(qp) * 4096 + ldsc]);       \
    GL8(_s + (size_t)(128 + (qp) * 64) * K, &lds[bf][0][1][(qp) * 4096 + ldsc]); }
#define STAGE_B(bf, kt, hf) {                                                          \
    const u16* _s = Bsrc + (size_t)(kt) * 64;                                          \
    GL8(_s + (size_t)((hf) * 128) * K,      &lds[bf][1][hf][ldsc]);                    \
    GL8(_s + (size_t)((hf) * 128 + 64) * K, &lds[bf][1][hf][4096 + ldsc]); }
#define LDA(bf, mi, kk) \
  (*(const short8*)((const char*)&lds[bf][0][wm][0] + (mi) * 2048 + (kk) * 1024 + fr_off))
#define LDB(bf, ni, kk) \
  (*(const short8*)((const char*)&lds[bf][1][wn >> 1][0] + ((wn & 1) * 4 + (ni)) * 2048 + (kk) * 1024 + fr_off))

  f32x4 acc[8][4] = {};
  short8 bfr[4][2], af[2][2];

  STAGE_B(0, 0, 0); STAGE_B(0, 0, 1); STAGE_A(0, 0, 0); STAGE_A(0, 0, 1);
  STAGE_B(1, 1, 0); STAGE_B(1, 1, 1); STAGE_A(1, 1, 0);
  asm volatile("s_waitcnt vmcnt(6)" ::: "memory");
  __builtin_amdgcn_s_barrier();

#define PHASE(q, STG, VMW)                                                             \
    _Pragma("unroll") for (int i = 0; i < 2; ++i)                                      \
      _Pragma("unroll") for (int kk = 0; kk < 2; ++kk) af[i][kk] = LDA(c, 2 * (q) + i, kk); \
    STG; VMW;                                                                          \
    __builtin_amdgcn_s_barrier();                                                      \
    asm volatile("s_waitcnt lgkmcnt(0)" ::: "memory");                                 \
    __builtin_amdgcn_sched_barrier(0);                                                 \
    __builtin_amdgcn_s_setprio(1);                                                     \
    _Pragma("unroll") for (int i = 0; i < 2; ++i)                                      \
      _Pragma("unroll") for (int ni = 0; ni < 4; ++ni)                                 \
        _Pragma("unroll") for (int kk = 0; kk < 2; ++kk)                               \
          acc[2 * (q) + i][ni] = __builtin_amdgcn_mfma_f32_16x16x32_bf16(              \
              af[i][kk], bfr[ni][kk], acc[2 * (q) + i][ni], 0, 0, 0);                  \
    __builtin_amdgcn_s_setprio(0);                                                     \
    __builtin_amdgcn_s_barrier();

  for (int T = 0; T < nt; ++T) {
    const int c = T & 1;
#pragma unroll
    for (int ni = 0; ni < 4; ++ni)
#pragma unroll
      for (int kk = 0; kk < 2; ++kk) bfr[ni][kk] = LDB(c, ni, kk);
    PHASE(0, if (T + 1 < nt) STAGE_A(c ^ 1, T + 1, 1), )
    PHASE(1, if (T + 2 < nt) STAGE_B(c, T + 2, 0), )
    PHASE(2, if (T + 2 < nt) STAGE_B(c, T + 2, 1), )
    PHASE(3, if (T + 2 < nt) STAGE_A(c, T + 2, 0),
          if (T + 2 >= nt) { asm volatile("s_waitcnt vmcnt(0)" ::: "memory"); }
          else             { asm volatile("s_waitcnt vmcnt(6)" ::: "memory"); })
  }
#undef PHASE
#undef LDA
#undef LDB
#undef STAGE_A
#undef STAGE_B
#undef GL8

#pragma unroll
  for (int mi = 0; mi < 8; ++mi) {
#pragma unroll
    for (int ni = 0; ni < 4; ++ni) {
#pragma unroll
      for (int r = 0; r < 4; ++r) {
        int row = m0 + wm * 128 + mi * 16 + quad * 4 + r;
        int col = n0 + wn * 64 + ni * 16 + l16;
        if (OUTF32)
          ((float*)Cp)[(size_t)row * N + col] = acc[mi][ni][r];
        else
          ((u16*)Cp)[(size_t)row * N + col] = f2b(acc[mi][ni][r]);
      }
    }
  }
}

// ---------------- RoPE + rearrange ----------------
__global__ void rope_kernel(const u16* __restrict__ qkv, const float* __restrict__ cs,
                            const float* __restrict__ sn, u16* __restrict__ Qr,
                            u16* __restrict__ Kr) {
  int row = blockIdx.x;          // b*S + s
  int b = row >> 11, s = row & 2047;
  int d = threadIdx.x;           // 0..255
  const u16* qrow = qkv + (size_t)row * QKVN_;
  float c = cs[(size_t)row * D_ + d];
  float si = sn[(size_t)row * D_ + d];
  int dp = (d < 128) ? d + 128 : d - 128;
  float sgn = (d < 128) ? -1.f : 1.f;
#pragma unroll
  for (int h = 0; h < H_; ++h) {
    float v = b2f(qrow[h * D_ + d]);
    float p = sgn * b2f(qrow[h * D_ + dp]);
    Qr[((size_t)(b * H_ + h) * S_ + s) * D_ + d] = f2b(v * c + p * si);
  }
#pragma unroll
  for (int g = 0; g < KVH_; ++g) {
    float v = b2f(qrow[2048 + g * D_ + d]);
    float p = sgn * b2f(qrow[2048 + g * D_ + dp]);
    Kr[((size_t)(b * KVH_ + g) * S_ + s) * D_ + d] = f2b(v * c + p * si);
  }
}

// ---------------- V transpose: qkv v-part -> Vt (B,KVH,D,S) ----------------
__global__ void transpose_v(const u16* __restrict__ qkv, u16* __restrict__ Vt) {
  __shared__ u16 tile[64][72];
  int d0 = blockIdx.x * 64, s0 = blockIdx.y * 64, g = blockIdx.z; // g = b*KVH+kvh
  int b = g >> 2, kvh = g & 3;
  int t = threadIdx.x;
#pragma unroll
  for (int i = 0; i < 16; ++i) {
    int e = i * 256 + t;
    int r = e >> 6, c = e & 63;
    tile[r][c] = qkv[(size_t)(b * S_ + s0 + r) * QKVN_ + 3072 + kvh * D_ + d0 + c];
  }
  __syncthreads();
#pragma unroll
  for (int i = 0; i < 16; ++i) {
    int e = i * 256 + t;
    int orow = e >> 6, ocol = e & 63;
    Vt[((size_t)g * D_ + d0 + orow) * S_ + s0 + ocol] = tile[ocol][orow];
  }
}

// ---------------- flash attention v8c: v8b + VALU cuts ----------------
// Structure identical to v8b (proven 82.0us, FETCH 26.7MB via XCD h-pin).
// VALU reduction only:
//  - v_cvt_pk_bf16_f32 asm replaces f2b-pair+or packing (~28 -> 4 instrs/iter)
//  - folded-constant exp: E = 2^(s*0.0036067), ee = 2^(rcp*(-144.2695)) via raw
//    v_exp_f32 (saves the 0.0025/-100 muls and __expf's ln2 mul; same underflow)
__global__ __launch_bounds__(256, 2) void attn_kernel(
    const u16* __restrict__ Qr, const u16* __restrict__ Kr, const u16* __restrict__ Vt,
    float* __restrict__ Op0, float* __restrict__ Op1,
    float* __restrict__ Lp0, float* __restrict__ Lp1) {
  __shared__ u16 Ks[2][32 * 256]; // 2x16 KB, chunk-swizzled (^ sw(row))
  __shared__ u16 Vs[2][32 * 256]; // 2x16 KB, chunk-swizzled (^ (d>>1)&3)
  int bx = blockIdx.x;
  int h = bx & 7;                 // XCD pin: round-robin dispatch -> XCD = bx%8
  int u = bx >> 4;
  int sp = (bx >> 3) & 1;
  int kvh = h >> 1;  // N_REP = 2
  int tid = threadIdx.x, wave = tid >> 6, lane = tid & 63;
  int quad = lane >> 4, l16 = lane & 15;
  float* Op = sp ? Op1 : Op0;
  float* Lp = sp ? Lp1 : Lp0;
  int ksrc_s[4], ksrc_c[4], vsrc_d[4], vsrc_s[4];
#pragma unroll
  for (int i = 0; i < 4; ++i) {
    int p = i * 256 + tid;
    int sK = p >> 5;
    ksrc_s[i] = sK;
    ksrc_c[i] = (p & 31) ^ ((sK & 3) | (((sK >> 3) & 1) << 2));
    vsrc_d[i] = p >> 2;
    vsrc_s[i] = (p & 3) ^ ((p >> 3) & 3);
  }
  // K-fragment read geometry (swapped-QK, permuted rows):
  const int kg = l16 >> 2, ka = l16 & 3;
  const int srow0 = 8 * kg + ka;           // n=0; n=1 adds 4
  const int ksw = ka | ((kg & 1) << 2);    // sw(srow), same for n=0,1

  for (int part = 0; part < 2; ++part) {
    int b = part;
    int qt = (part == 0) ? u : (31 - u);
    int q0 = qt * 64;
    int beg = sp ? (qt + 1) : 0;
    int end = sp ? (2 * qt + 2) : (qt + 1);
    const u16* Qbase = Qr + ((size_t)(b * H_ + h) * S_ + q0 + wave * 16 + l16) * D_;
    short8 qf[8];
#pragma unroll
    for (int kk = 0; kk < 8; ++kk)
      qf[kk] = *(const short8*)(Qbase + kk * 32 + quad * 8);
    const u16* Kbase = Kr + (size_t)(b * KVH_ + kvh) * S_ * D_;
    const u16* Vbase = Vt + (size_t)(b * KVH_ + kvh) * D_ * S_;
    float lp = 0.f;
    f32x4 o_acc[16] = {};
    const int qq = q0 + wave * 16 + l16;

#define STAGE(KT, BUF)                                                                   \
    {                                                                                    \
      int k0s = (KT) * 32;                                                               \
      _Pragma("unroll") for (int i = 0; i < 4; ++i) {                                    \
        int p = i * 256 + tid;                                                           \
        __builtin_amdgcn_global_load_lds(                                                \
            (const __attribute__((address_space(1))) void*)(Kbase +                      \
                (size_t)(k0s + ksrc_s[i]) * D_ + ksrc_c[i] * 8),                         \
            (__attribute__((address_space(3))) void*)(&Ks[BUF][0] + p * 8), 16, 0, 0);   \
      }                                                                                  \
      _Pragma("unroll") for (int i = 0; i < 4; ++i) {                                    \
        int p = i * 256 + tid;                                                           \
        __builtin_amdgcn_global_load_lds(                                                \
            (const __attribute__((address_space(1))) void*)(Vbase +                      \
                (size_t)vsrc_d[i] * S_ + k0s + vsrc_s[i] * 8),                           \
            (__attribute__((address_space(3))) void*)(&Vs[BUF][0] + p * 8), 16, 0, 0);   \
      }                                                                                  \
    }

    STAGE(beg, 0);
    __syncthreads();
    for (int kt = beg; kt < end; ++kt) {
      int k0 = kt * 32;
      int cur = (kt - beg) & 1;
      if (kt + 1 < end) STAGE(kt + 1, cur ^ 1);
      // S^T = K Q^T (A = permuted K-tile, B = Q)
      f32x4 sacc[2] = {};
      __builtin_amdgcn_s_setprio(1);
#pragma unroll
      for (int n = 0; n < 2; ++n) {
        const u16* kb = &Ks[cur][0] + (srow0 + 4 * n) * 256;
#pragma unroll
        for (int kk = 0; kk < 8; ++kk) {
          int phys = (kk * 4 + quad) ^ ksw;
          short8 kfr = *(const short8*)(kb + phys * 8);
          sacc[n] = __builtin_amdgcn_mfma_f32_16x16x32_bf16(kfr, qf[kk], sacc[n], 0, 0, 0);
        }
      }
      __builtin_amdgcn_s_setprio(0);
      // fused softcap+softmax: ee = exp(50*tanh(s/16/50)-50) = exp(-100/(E+1))
      // exp2 form: E = 2^(s*0.0025*log2e), ee = 2^(-100*log2e * rcp(E+1))
      bool full = (k0 + 31 <= q0 + wave * 16);  // wave-uniform
#pragma unroll
      for (int n = 0; n < 2; ++n) {
#pragma unroll
        for (int r = 0; r < 4; ++r) {
          float E = exp2_raw(sacc[n][r] * 0.0036067376f);
          float ee = exp2_raw(__frcp_rn(E + 1.0f) * -144.2695041f);
          if (!full) {
            int key = k0 + 8 * quad + 4 * n + r;   // lane holds keys 8*quad + 4n + r
            ee = (key <= qq) ? ee : 0.0f;
          }
          lp += ee;
          sacc[n][r] = ee;
        }
      }
      // pack P in-register: frag elem j = key 8*quad+j, j = 4n+r
      union { short8 s8; unsigned int d[4]; } pu;
      pu.d[0] = cvt_pk_bf16(sacc[0][0], sacc[0][1]);
      pu.d[1] = cvt_pk_bf16(sacc[0][2], sacc[0][3]);
      pu.d[2] = cvt_pk_bf16(sacc[1][0], sacc[1][1]);
      pu.d[3] = cvt_pk_bf16(sacc[1][2], sacc[1][3]);
      short8 pa = pu.s8;
      // O += P V  (pa is PV's A-fragment directly; no LDS round-trip)
      __builtin_amdgcn_s_setprio(1);
#pragma unroll
      for (int dt = 0; dt < 16; ++dt) {
        int d = dt * 16 + l16;
        int phys = quad ^ ((d >> 1) & 3);
        short8 vb = *(const short8*)(&Vs[cur][0] + d * 32 + phys * 8);
        o_acc[dt] = __builtin_amdgcn_mfma_f32_16x16x32_bf16(pa, vb, o_acc[dt], 0, 0, 0);
      }
      __builtin_amdgcn_s_setprio(0);
      __syncthreads();  // buffer handoff (prefetch long since landed)
    }
#undef STAGE
    // denominator partial: lane holds sum for q=l16 over its 8 keys/iter; reduce quads
    lp += __shfl_xor(lp, 16, 64);
    lp += __shfl_xor(lp, 32, 64);
    if (lane < 16)
      Lp[((size_t)(b * H_ + h)) * S_ + q0 + wave * 16 + lane] = lp;
    // unnormalized fp32 partial O (row q = quad*4+r, col d = dt*16+l16)
#pragma unroll
    for (int dt = 0; dt < 16; ++dt)
#pragma unroll
      for (int r = 0; r < 4; ++r) {
        int row = b * S_ + q0 + wave * 16 + quad * 4 + r;
        int col = h * D_ + dt * 16 + l16;
        Op[(size_t)row * AON_ + col] = o_acc[dt][r];
      }
  }
}

// ---------------- combine splits: Ao = (O0+O1) / (l0+l1), bf16 ----------------
__global__ void combine_kernel(const float* __restrict__ Op0, const float* __restrict__ Op1,
                               const float* __restrict__ Lp0, const float* __restrict__ Lp1,
                               u16* __restrict__ Ao) {
  size_t idx = (size_t)blockIdx.x * 256 + threadIdx.x;
  size_t row = idx >> 9;
  int c4 = ((int)idx & 511) * 4;
  const float4 a = *(const float4*)(Op0 + row * AON_ + c4);
  const float4 b4 = *(const float4*)(Op1 + row * AON_ + c4);
  int b = (int)(row >> 11), s = (int)row & 2047;
  int h = c4 >> 8;
  size_t li = ((size_t)(b * H_ + h)) * S_ + s;
  float inv = 1.0f / (Lp0[li] + Lp1[li]);
  unsigned int lo = (unsigned int)f2b((a.x + b4.x) * inv) | ((unsigned int)f2b((a.y + b4.y) * inv) << 16);
  unsigned int hi = (unsigned int)f2b((a.z + b4.z) * inv) | ((unsigned int)f2b((a.w + b4.w) * inv) << 16);
  uint2 o; o.x = lo; o.y = hi;
  *(uint2*)(Ao + row * AON_ + c4) = o;
}

extern "C" void kernel_launch(void* const* d_in, const int* in_sizes, int n_in,
                              void* d_out, int out_size, void* d_ws, size_t ws_size,
                              hipStream_t stream) {
  const float* hidden = (const float*)d_in[0];
  const float* cosp = (const float*)d_in[1];
  const float* sinp = (const float*)d_in[2];
  const float* Wq = (const float*)d_in[4];
  const float* Wk = (const float*)d_in[5];
  const float* Wv = (const float*)d_in[6];
  const float* Wo = (const float*)d_in[7];

  u16* hs  = (u16*)d_ws;                              // 4096 x 2304 (dead after gemm1)
  u16* WT  = hs  + (size_t)4096 * HID_;               // 4096 x 2304 (dead after gemm1)
  u16* WoT = WT  + (size_t)4096 * HID_;               // 2304 x 2048 (live till gemm2)
  u16* qkv = WoT + (size_t)HID_ * AON_;               // 4096 x 4096 (dead after rope/transpose_v)
  u16* Qr  = qkv + (size_t)4096 * QKVN_;              // B,H,S,D
  u16* Kr  = Qr  + (size_t)B_ * H_ * S_ * D_;         // B,KVH,S,D
  u16* Vt  = Kr  + (size_t)B_ * KVH_ * S_ * D_;       // B,KVH,D,S
  u16* Ao  = Vt  + (size_t)B_ * KVH_ * S_ * D_;       // 4096 x 2048
  float* Lp0 = (float*)(Ao + (size_t)4096 * AON_);    // 2*8*2048 fp32
  float* Lp1 = Lp0 + (size_t)B_ * H_ * S_;            // 2*8*2048 fp32
  float* Op0 = (float*)hs;    // hs+WT region: 37.7 MB available >= 33.5
  float* Op1 = (float*)qkv;   // qkv region: 33.5 MB, exact fit

  cast_kernel<<<9216, 256, 0, stream>>>(hidden, hs);
  transpose_cast_all<<<dim3(36, 36, 4), 256, 0, stream>>>(
      Wq, Wk, Wv, Wo, WT, WT + (size_t)2048 * HID_, WT + (size_t)3072 * HID_, WoT);
  gemm_bt8<0><<<dim3(16, 16), 512, 0, stream>>>(hs, WT, qkv, 4096, QKVN_, HID_);
  rope_kernel<<<4096, 256, 0, stream>>>(qkv, cosp, sinp, Qr, Kr);
  transpose_v<<<dim3(4, 32, 8), 256, 0, stream>>>(qkv, Vt);
  attn_kernel<<<dim3(512), 256, 0, stream>>>(Qr, Kr, Vt, Op0, Op1, Lp0, Lp1);
  combine_kernel<<<16384, 256, 0, stream>>>(Op0, Op1, Lp0, Lp1, Ao);
  gemm_bt8<1><<<dim3(9, 16), 512, 0, stream>>>(Ao, WoT, d_out, 4096, HID_, 2048);
}